// Round 2
// baseline (4347.182 us; speedup 1.0000x reference)
//
#include <hip/hip_runtime.h>
#include <math.h>

// Problem dims (fixed by reference)
#define BS      256
#define FLAT    8192        // 256*32 flattened history
#define H       1024
#define G4      4096        // 4*H
#define T_STEPS 64
#define AD      16
#define NOUT    16

__device__ __forceinline__ float sigf(float x) {
    return 1.0f / (1.0f + __expf(-x));
}
__device__ __forceinline__ float tanh_fast(float x) {
    float a = fabsf(x);
    float e = __expf(-2.0f * a);
    float r = (1.0f - e) / (1.0f + e);
    return copysignf(r, x);
}

// =====================================================================
// Kernel A: c0 = relu(flat@Wc + bc), h0 = relu(flat@Wh + bh)
// grid 256 = 2 matrices x 8 rowblocks(32) x 16 colblocks(64); block 256
// =====================================================================
__global__ __launch_bounds__(256) void init_gemm(
    const float* __restrict__ hist,   // [256][8192]
    const float* __restrict__ Wc, const float* __restrict__ bc,
    const float* __restrict__ Wh, const float* __restrict__ bh,
    float* __restrict__ c0, float* __restrict__ h0)
{
    __shared__ float sA[32 * 34];   // [kk][row] transposed, pad 34
    __shared__ float sB[32 * 64];   // [kk][col]

    const int wg  = blockIdx.x;
    const int mat = wg >> 7;
    const int m   = wg & 127;
    const int r0  = (m >> 4) * 32;
    const int cc0 = (m & 15) * 64;

    const float* W    = mat ? Wh : Wc;
    const float* bias = mat ? bh : bc;
    float*       dst  = mat ? h0 : c0;

    const int tid = threadIdx.x;
    const int tx  = tid & 15;   // 16 col groups x 4 cols
    const int ty  = tid >> 4;   // 16 row groups x 2 rows

    float acc[2][4] = {};

    for (int k0 = 0; k0 < FLAT; k0 += 32) {
        {   // stage A chunk transposed: lanes consecutive in kk -> coalesced
            int kk = tid & 31, rr = tid >> 5;
            #pragma unroll
            for (int it = 0; it < 4; ++it) {
                int row = rr + it * 8;
                sA[kk * 34 + row] = hist[(size_t)(r0 + row) * FLAT + k0 + kk];
            }
        }
        {   // stage B chunk: lanes consecutive in col -> coalesced
            int col = tid & 63, kq = tid >> 6;
            #pragma unroll
            for (int it = 0; it < 8; ++it) {
                int k = kq + it * 4;
                sB[k * 64 + col] = W[(size_t)(k0 + k) * H + cc0 + col];
            }
        }
        __syncthreads();
        #pragma unroll
        for (int kk = 0; kk < 32; ++kk) {
            const float2 a2 = *(const float2*)&sA[kk * 34 + ty * 2];
            const float4 b4 = *(const float4*)&sB[kk * 64 + tx * 4];
            acc[0][0] = fmaf(a2.x, b4.x, acc[0][0]);
            acc[0][1] = fmaf(a2.x, b4.y, acc[0][1]);
            acc[0][2] = fmaf(a2.x, b4.z, acc[0][2]);
            acc[0][3] = fmaf(a2.x, b4.w, acc[0][3]);
            acc[1][0] = fmaf(a2.y, b4.x, acc[1][0]);
            acc[1][1] = fmaf(a2.y, b4.y, acc[1][1]);
            acc[1][2] = fmaf(a2.y, b4.z, acc[1][2]);
            acc[1][3] = fmaf(a2.y, b4.w, acc[1][3]);
        }
        __syncthreads();
    }

    const float4 bv = *(const float4*)&bias[cc0 + tx * 4];
    #pragma unroll
    for (int i = 0; i < 2; ++i) {
        float4 o;
        o.x = fmaxf(acc[i][0] + bv.x, 0.f);
        o.y = fmaxf(acc[i][1] + bv.y, 0.f);
        o.z = fmaxf(acc[i][2] + bv.z, 0.f);
        o.w = fmaxf(acc[i][3] + bv.w, 0.f);
        *(float4*)&dst[(size_t)(r0 + ty * 2 + i) * H + cc0 + tx * 4] = o;
    }
}

// =====================================================================
// Kernel S: ONE LSTM step (launched 64x). Kernel boundaries give
// device-wide visibility of h_t — no cooperative launch, no grid.sync.
// grid 256 WGs = 2 rowblocks(128 rows) x 128 hidblocks(8 hidden units).
// block 512 (8 waves/CU -> 2/SIMD). Gate-col c in [0,32): gate=c>>3,
// hid=c&7 (so the 4 gates of one hidden unit live in one WG).
// c-state: global RMW, each (row,hid) owned by exactly one thread.
// =====================================================================
__global__ __launch_bounds__(512) void lstm_step(
    const float* __restrict__ action,  // [256][64][16]
    const float* __restrict__ Wi,      // [16][4096]
    const float* __restrict__ Wr,      // [1024][4096]
    const float* __restrict__ bg,      // [4096]
    const float* __restrict__ hprev,   // [256][1024]
    float* __restrict__ cbuf,          // [256][1024] read-modify-write
    float* __restrict__ hout,          // [256][1024]
    int t)
{
    __shared__ float sWr[32 * 32];     // [kk][c] chunk of Wr slice
    __shared__ float sWi[16 * 32];     // [a][c]
    __shared__ float sBg[32];
    __shared__ float scr[4608];        // action tile [128][17] / hT [32][132] / gates [128][36]

    const int wg = blockIdx.x;
    const int r0 = (wg >> 7) * 128;
    const int j0 = (wg & 127) * 8;

    const int tid = threadIdx.x;
    const int tx  = tid & 7;    // 8 col groups x 4 gate-cols
    const int ty  = tid >> 3;   // 64 row groups x 2 rows

    // ---- stage Wi slice, bg slice, action tile ----
    {
        int a = tid >> 5, c = tid & 31;   // 512 threads = 16x32 exactly
        sWi[tid] = Wi[(size_t)a * G4 + ((c >> 3) << 10) + j0 + (c & 7)];
    }
    if (tid < 32) sBg[tid] = bg[((tid >> 3) << 10) + j0 + (tid & 7)];
    for (int idx = tid; idx < 128 * 16; idx += 512) {
        int row = idx >> 4, a = idx & 15;
        scr[row * 17 + a] = action[(size_t)(r0 + row) * (T_STEPS * AD) + t * AD + a];
    }
    __syncthreads();

    // ---- acc = bg + x_t @ Wi  (K=16, fused xg) ----
    float acc[2][4];
    {
        const float4 b0 = *(const float4*)&sBg[tx * 4];
        #pragma unroll
        for (int i = 0; i < 2; ++i) {
            acc[i][0] = b0.x; acc[i][1] = b0.y; acc[i][2] = b0.z; acc[i][3] = b0.w;
        }
        #pragma unroll
        for (int a = 0; a < AD; ++a) {
            const float4 w4 = *(const float4*)&sWi[a * 32 + tx * 4];
            #pragma unroll
            for (int i = 0; i < 2; ++i) {
                float av = scr[(ty * 2 + i) * 17 + a];
                acc[i][0] = fmaf(av, w4.x, acc[i][0]);
                acc[i][1] = fmaf(av, w4.y, acc[i][1]);
                acc[i][2] = fmaf(av, w4.z, acc[i][2]);
                acc[i][3] = fmaf(av, w4.w, acc[i][3]);
            }
        }
    }
    __syncthreads();   // scr reused as hT chunk

    // ---- acc += h_{t-1} @ Wr_slice, K=1024 in chunks of 32 ----
    for (int kc = 0; kc < H; kc += 32) {
        {   // stage hT chunk [kk=32][row=128] transposed; coalesced global reads
            int kk = tid & 31, rr = tid >> 5;   // rr in [0,16)
            #pragma unroll
            for (int it = 0; it < 8; ++it) {
                int row = rr + it * 16;
                scr[kk * 132 + row] = hprev[(size_t)(r0 + row) * H + kc + kk];
            }
        }
        {   // stage Wr chunk [kk=32][c=32]
            #pragma unroll
            for (int u = 0; u < 2; ++u) {
                int idx = tid + u * 512;
                int kk = idx >> 5, c = idx & 31;
                sWr[idx] = Wr[(size_t)(kc + kk) * G4 + ((c >> 3) << 10) + j0 + (c & 7)];
            }
        }
        __syncthreads();
        #pragma unroll
        for (int kk = 0; kk < 32; ++kk) {
            const float4 w4 = *(const float4*)&sWr[kk * 32 + tx * 4];
            const float2 h2 = *(const float2*)&scr[kk * 132 + ty * 2];
            acc[0][0] = fmaf(h2.x, w4.x, acc[0][0]);
            acc[0][1] = fmaf(h2.x, w4.y, acc[0][1]);
            acc[0][2] = fmaf(h2.x, w4.z, acc[0][2]);
            acc[0][3] = fmaf(h2.x, w4.w, acc[0][3]);
            acc[1][0] = fmaf(h2.y, w4.x, acc[1][0]);
            acc[1][1] = fmaf(h2.y, w4.y, acc[1][1]);
            acc[1][2] = fmaf(h2.y, w4.z, acc[1][2]);
            acc[1][3] = fmaf(h2.y, w4.w, acc[1][3]);
        }
        __syncthreads();
    }

    // ---- exchange gate values through LDS: scr[row*36 + c] ----
    #pragma unroll
    for (int i = 0; i < 2; ++i)
        #pragma unroll
        for (int j = 0; j < 4; ++j)
            scr[(ty * 2 + i) * 36 + tx * 4 + j] = acc[i][j];
    __syncthreads();

    // ---- elementwise LSTM cell update; c RMW in global (unique owner) ----
    const int e_hid = tid & 7;
    const int e_rg  = tid >> 3;   // [0,64)
    #pragma unroll
    for (int i = 0; i < 2; ++i) {
        int row = e_rg * 2 + i;
        float gi = scr[row * 36 + 0  + e_hid];
        float gf = scr[row * 36 + 8  + e_hid];
        float gg = scr[row * 36 + 16 + e_hid];
        float go = scr[row * 36 + 24 + e_hid];
        size_t off = (size_t)(r0 + row) * H + j0 + e_hid;
        float cv = sigf(gf) * cbuf[off] + sigf(gi) * tanh_fast(gg);
        cbuf[off] = cv;
        hout[off] = sigf(go) * tanh_fast(cv);
    }
}

// =====================================================================
// Kernel B: out[b][t][o] = hs[t][b][:] @ Wo[:,o] + bo[o]
// =====================================================================
__global__ __launch_bounds__(256) void out_proj(
    const float* __restrict__ hs,   // [64][256][1024]
    const float* __restrict__ Wo,   // [1024][16]
    const float* __restrict__ bo,   // [16]
    float* __restrict__ out)        // [256][64][16]
{
    __shared__ float sWo[H * NOUT];
    const int tid = threadIdx.x;
    for (int idx = tid; idx < H * NOUT; idx += 256) sWo[idx] = Wo[idx];
    __syncthreads();

    const int o    = tid & 15;
    const int pl   = tid >> 4;                  // 16 (b,t) pairs per WG
    const int pair = blockIdx.x * 16 + pl;      // pair = b*64 + t
    const int b    = pair >> 6;
    const int t    = pair & 63;
    const float* hrow = hs + (size_t)t * BS * H + (size_t)b * H;

    float acc = bo[o];
    for (int k = 0; k < H; k += 4) {
        const float4 hv = *(const float4*)&hrow[k];
        acc = fmaf(hv.x, sWo[(k + 0) * 16 + o], acc);
        acc = fmaf(hv.y, sWo[(k + 1) * 16 + o], acc);
        acc = fmaf(hv.z, sWo[(k + 2) * 16 + o], acc);
        acc = fmaf(hv.w, sWo[(k + 3) * 16 + o], acc);
    }
    out[(size_t)pair * 16 + o] = acc;
}

// =====================================================================
extern "C" void kernel_launch(void* const* d_in, const int* in_sizes, int n_in,
                              void* d_out, int out_size, void* d_ws, size_t ws_size,
                              hipStream_t stream)
{
    const float* hist = (const float*)d_in[0];
    const float* act  = (const float*)d_in[1];
    const float* Wc   = (const float*)d_in[2];
    const float* bc   = (const float*)d_in[3];
    const float* Wh   = (const float*)d_in[4];
    const float* bh   = (const float*)d_in[5];
    const float* Wi   = (const float*)d_in[6];
    const float* Wr   = (const float*)d_in[7];
    const float* bg   = (const float*)d_in[8];
    const float* Wo   = (const float*)d_in[9];
    const float* bo   = (const float*)d_in[10];
    float* out = (float*)d_out;

    // workspace layout (~69 MB): c | h0 | hs
    float* cbuf = (float*)d_ws;                  // 256*1024 (live c state)
    float* h0   = cbuf + BS * H;                 // 256*1024
    float* hs   = h0 + BS * H;                   // 64*256*1024

    init_gemm<<<dim3(256), dim3(256), 0, stream>>>(hist, Wc, bc, Wh, bh, cbuf, h0);

    for (int t = 0; t < T_STEPS; ++t) {
        const float* hprev = (t == 0) ? h0 : hs + (size_t)(t - 1) * BS * H;
        float* hout = hs + (size_t)t * BS * H;
        lstm_step<<<dim3(256), dim3(512), 0, stream>>>(act, Wi, Wr, bg,
                                                       hprev, cbuf, hout, t);
    }

    out_proj<<<dim3(1024), dim3(256), 0, stream>>>(hs, Wo, bo, out);
}

// Round 4
// 815.206 us; speedup vs baseline: 5.3326x; 5.3326x over previous
//
#include <hip/hip_runtime.h>
#include <math.h>

// Problem dims (fixed by reference)
#define BS      256
#define FLAT    8192
#define H       1024
#define G4      4096
#define T_STEPS 64
#define AD      16
#define NOUT    16

typedef __attribute__((ext_vector_type(8))) short    bf16x8;   // MFMA A/B frag
typedef __attribute__((ext_vector_type(4))) float    f32x4;    // MFMA C/D frag
typedef __attribute__((ext_vector_type(8))) unsigned short u16x8;
typedef __attribute__((ext_vector_type(4))) unsigned short u16x4;

__device__ __forceinline__ float sigf(float x) { return 1.0f / (1.0f + __expf(-x)); }
__device__ __forceinline__ float tanh_fast(float x) {
    float a = fabsf(x);
    float e = __expf(-2.0f * a);
    float r = (1.0f - e) / (1.0f + e);
    return copysignf(r, x);
}
__device__ __forceinline__ unsigned short f2bf(float x) {   // RNE
    unsigned int u = __float_as_uint(x);
    unsigned int r = (u + 0x7FFFu + ((u >> 16) & 1u)) >> 16;
    return (unsigned short)r;
}
__device__ __forceinline__ float bf2f(unsigned short u) {
    return __uint_as_float(((unsigned int)u) << 16);
}

// ws layout (bytes) — total ~42.3 MB (proven ws >= 66 MB in round 2)
#define OFF_WRP  (1u<<20)                       // Wr packed bf16, 8 MB
#define OFF_WIP  (OFF_WRP + (8u<<20))           // Wi packed bf16, 256 KB
#define OFF_BGP  (OFF_WIP + (256u<<10))         // bg packed f32, 16 KB
#define OFF_HPA  (OFF_BGP + (16u<<10))          // h packed bf16 ping, 512 KB
#define OFF_HPB  (OFF_HPA + (512u<<10))         // h packed bf16 pong, 512 KB
#define OFF_HS   (OFF_HPB + (512u<<10))         // hs bf16 [64][256][1024], 32 MB
#define OFF_PART (OFF_HS + 48u*BS*H*2u)         // split-K partials f32 8MB (overlay hs t>=48)

// =====================================================================
// Wr pack: Wp[nb][kc][nt][lane][i] = Wr[kc*32 + (l>>4)*8 + i][nt*1024 + nb*16 + (l&15)]
// fragment-linear: a wave's B-frag is 16 consecutive bytes per lane.
// =====================================================================
__global__ __launch_bounds__(256) void pack_wr(const float* __restrict__ Wr,
                                               unsigned short* __restrict__ Wp)
{
    int g  = blockIdx.x * 256 + threadIdx.x;     // 0..524287
    int l  = g & 63;
    int nt = (g >> 6) & 3;
    int kc = (g >> 8) & 31;
    int nb = g >> 13;
    int col   = nt * 1024 + nb * 16 + (l & 15);
    int kbase = kc * 32 + (l >> 4) * 8;
    u16x8 o;
    #pragma unroll
    for (int i = 0; i < 8; ++i)
        o[i] = f2bf(Wr[(size_t)(kbase + i) * G4 + col]);
    *(u16x8*)&Wp[(size_t)g * 8] = o;
}

// Wi pack (K zero-padded 16->32), same frag layout, one kc group.
__global__ __launch_bounds__(256) void pack_wi(const float* __restrict__ Wi,
                                               unsigned short* __restrict__ Wp)
{
    int g  = blockIdx.x * 256 + threadIdx.x;     // 0..16383
    int l  = g & 63;
    int nt = (g >> 6) & 3;
    int nb = g >> 8;
    int col   = nt * 1024 + nb * 16 + (l & 15);
    int kbase = (l >> 4) * 8;
    u16x8 o;
    #pragma unroll
    for (int i = 0; i < 8; ++i)
        o[i] = (kbase + i < AD) ? f2bf(Wi[(size_t)(kbase + i) * G4 + col]) : (unsigned short)0;
    *(u16x8*)&Wp[(size_t)g * 8] = o;
}

// bg pack: bgp[nb*64 + nt*16 + jj] = bg[nt*1024 + nb*16 + jj]
__global__ __launch_bounds__(256) void pack_bg(const float* __restrict__ bg,
                                               float* __restrict__ bgp)
{
    int t = blockIdx.x * 256 + threadIdx.x;      // 0..4095
    int jj = t & 15, nt = (t >> 4) & 3, nb = t >> 6;
    bgp[t] = bg[nt * 1024 + nb * 16 + jj];
}

// =====================================================================
// init GEMM, split-K x4: partial[ks][mat][256][1024] (no bias/relu yet)
// grid 1024 = ks(4) x mat(2) x 8 rowblocks(32) x 16 colblocks(64)
// =====================================================================
__global__ __launch_bounds__(256) void init_gemm_sk(
    const float* __restrict__ hist,
    const float* __restrict__ Wc, const float* __restrict__ Wh,
    float* __restrict__ partial)
{
    __shared__ float sA[32 * 34];
    __shared__ float sB[32 * 64];

    const int wg  = blockIdx.x;
    const int ks  = wg >> 8;
    const int mat = (wg >> 7) & 1;
    const int m   = wg & 127;
    const int r0  = (m >> 4) * 32;
    const int cc0 = (m & 15) * 64;
    const float* W = mat ? Wh : Wc;

    const int tid = threadIdx.x;
    const int tx  = tid & 15;
    const int ty  = tid >> 4;

    float acc[2][4] = {};
    const int kend = ks * 2048 + 2048;
    for (int k0 = ks * 2048; k0 < kend; k0 += 32) {
        {
            int kk = tid & 31, rr = tid >> 5;
            #pragma unroll
            for (int it = 0; it < 4; ++it) {
                int row = rr + it * 8;
                sA[kk * 34 + row] = hist[(size_t)(r0 + row) * FLAT + k0 + kk];
            }
        }
        {
            int col = tid & 63, kq = tid >> 6;
            #pragma unroll
            for (int it = 0; it < 8; ++it) {
                int k = kq + it * 4;
                sB[k * 64 + col] = W[(size_t)(k0 + k) * H + cc0 + col];
            }
        }
        __syncthreads();
        #pragma unroll
        for (int kk = 0; kk < 32; ++kk) {
            const float2 a2 = *(const float2*)&sA[kk * 34 + ty * 2];
            const float4 b4 = *(const float4*)&sB[kk * 64 + tx * 4];
            acc[0][0] = fmaf(a2.x, b4.x, acc[0][0]);
            acc[0][1] = fmaf(a2.x, b4.y, acc[0][1]);
            acc[0][2] = fmaf(a2.x, b4.z, acc[0][2]);
            acc[0][3] = fmaf(a2.x, b4.w, acc[0][3]);
            acc[1][0] = fmaf(a2.y, b4.x, acc[1][0]);
            acc[1][1] = fmaf(a2.y, b4.y, acc[1][1]);
            acc[1][2] = fmaf(a2.y, b4.z, acc[1][2]);
            acc[1][3] = fmaf(a2.y, b4.w, acc[1][3]);
        }
        __syncthreads();
    }

    float* dst = partial + (size_t)(ks * 2 + mat) * BS * H;
    #pragma unroll
    for (int i = 0; i < 2; ++i) {
        float4 o = { acc[i][0], acc[i][1], acc[i][2], acc[i][3] };
        *(float4*)&dst[(size_t)(r0 + ty * 2 + i) * H + cc0 + tx * 4] = o;
    }
}

// reduce partials + bias + relu; c0 -> cbuf f32, h0 -> packed bf16 (frag-linear)
__global__ __launch_bounds__(256) void reduce_pack(
    const float* __restrict__ partial,
    const float* __restrict__ bc, const float* __restrict__ bh,
    float* __restrict__ cbuf, unsigned short* __restrict__ hp0)
{
    int e = blockIdx.x * 256 + threadIdx.x;      // 0..524287
    int mat = e >> 18;
    int rc  = e & 0x3FFFF;
    int row = rc >> 10, col = rc & 1023;
    float s = (mat ? bh : bc)[col];
    #pragma unroll
    for (int ks = 0; ks < 4; ++ks)
        s += partial[((size_t)(ks * 2 + mat) * BS + row) * H + col];
    s = fmaxf(s, 0.f);
    if (mat == 0) {
        cbuf[rc] = s;
    } else {
        int off = (row >> 6) * 65536 + (col >> 5) * 2048 + ((row >> 4) & 3) * 512
                + ((((col >> 3) & 3) << 4) + (row & 15)) * 8 + (col & 7);
        hp0[off] = f2bf(s);
    }
}

// =====================================================================
// LSTM step, MFMA bf16. grid 256 = mb(4: 64 rows) x nb(64: 16 hids x 4 gates)
// block 256 = 4 waves, wave w owns rows mb*64 + w*16 .. +15, all 64 N-cols.
// N-tile nt == gate (i,f,g,o) -> cell update is lane-local (no LDS exchange).
// A (h_prev) read as packed frags straight from global (L2-resident 512KB).
// B (Wr slice) staged to LDS double-buffered, frag-linear (conflict-free).
// =====================================================================
__global__ __launch_bounds__(256) void lstm_step(
    const float* __restrict__ act,            // [256][64][16]
    const unsigned short* __restrict__ Wip,   // packed
    const unsigned short* __restrict__ Wrp,   // packed
    const float* __restrict__ bgp,            // packed
    const unsigned short* __restrict__ Aprev, // h_{t-1} packed bf16
    unsigned short* __restrict__ Anext,       // h_t packed bf16
    float* __restrict__ cbuf,                 // [256][1024] f32 RMW
    unsigned short* __restrict__ hs_t,        // hs + t*BS*H (bf16)
    int t)
{
    __shared__ __align__(16) unsigned short sB[2][4096];   // 2 x 8KB
    __shared__ __align__(16) unsigned short sAct[64 * 32]; // [row][32], cols 16..31 zero

    const int tid = threadIdx.x;
    const int wg  = blockIdx.x;
    const int mb  = wg >> 6;          // 0..3
    const int nb  = wg & 63;          // 0..63
    const int wv  = tid >> 6;         // wave 0..3
    const int l   = tid & 63;

    // ---- stage action tile (f32 -> bf16), zero-pad k 16..31 ----
    {
        int row = tid >> 2, q = tid & 3;
        float4 v = *(const float4*)&act[((size_t)(mb * 64 + row) * T_STEPS + t) * AD + q * 4];
        u16x4 b; b[0] = f2bf(v.x); b[1] = f2bf(v.y); b[2] = f2bf(v.z); b[3] = f2bf(v.w);
        *(u16x4*)&sAct[row * 32 + q * 4] = b;
        u16x4 z = { 0, 0, 0, 0 };
        *(u16x4*)&sAct[row * 32 + 16 + q * 4] = z;
    }

    // ---- B chunk pointers (frag-linear pack, 8KB per K-chunk of 64) ----
    const u16x8* Bsrc = (const u16x8*)(Wrp + (size_t)nb * 65536);
    // chunk 0 -> LDS buf0 directly
    {
        u16x8 s0 = Bsrc[tid], s1 = Bsrc[256 + tid];
        *(u16x8*)&sB[0][tid * 8]         = s0;
        *(u16x8*)&sB[0][(256 + tid) * 8] = s1;
    }
    // chunk 1 -> regs
    u16x8 stg0 = Bsrc[512 + tid];
    u16x8 stg1 = Bsrc[768 + tid];

    // ---- A frag base (packed h_prev) ----
    const bf16x8* Asrc = ((const bf16x8*)Aprev) + mb * 8192 + wv * 64 + l;
    bf16x8 a0 = Asrc[0];
    bf16x8 a1 = Asrc[256];

    // ---- Wi frags + bias init ----
    f32x4 acc[4];
    {
        const bf16x8* WiB = ((const bf16x8*)Wip) + nb * 256;
        bf16x8 wb0 = WiB[0 * 64 + l], wb1 = WiB[1 * 64 + l],
               wb2 = WiB[2 * 64 + l], wb3 = WiB[3 * 64 + l];
        float g0 = bgp[nb * 64 +  0 + (l & 15)];
        float g1 = bgp[nb * 64 + 16 + (l & 15)];
        float g2 = bgp[nb * 64 + 32 + (l & 15)];
        float g3 = bgp[nb * 64 + 48 + (l & 15)];
        acc[0] = (f32x4){ g0, g0, g0, g0 };
        acc[1] = (f32x4){ g1, g1, g1, g1 };
        acc[2] = (f32x4){ g2, g2, g2, g2 };
        acc[3] = (f32x4){ g3, g3, g3, g3 };

        __syncthreads();   // sAct + sB[0] visible

        bf16x8 aa = *(const bf16x8*)&sAct[(wv * 16 + (l & 15)) * 32 + (l >> 4) * 8];
        acc[0] = __builtin_amdgcn_mfma_f32_16x16x32_bf16(aa, wb0, acc[0], 0, 0, 0);
        acc[1] = __builtin_amdgcn_mfma_f32_16x16x32_bf16(aa, wb1, acc[1], 0, 0, 0);
        acc[2] = __builtin_amdgcn_mfma_f32_16x16x32_bf16(aa, wb2, acc[2], 0, 0, 0);
        acc[3] = __builtin_amdgcn_mfma_f32_16x16x32_bf16(aa, wb3, acc[3], 0, 0, 0);
    }

    // ---- main K loop: 16 chunks of BK=64 (2 MFMA k-steps each) ----
    for (int c = 0; c < 16; ++c) {
        const int cb = c & 1;
        // current B frags from LDS (lane-consecutive 16B: conflict-free)
        bf16x8 bf00 = *(const bf16x8*)&sB[cb][(0 * 64 + l) * 8];
        bf16x8 bf01 = *(const bf16x8*)&sB[cb][(1 * 64 + l) * 8];
        bf16x8 bf02 = *(const bf16x8*)&sB[cb][(2 * 64 + l) * 8];
        bf16x8 bf03 = *(const bf16x8*)&sB[cb][(3 * 64 + l) * 8];
        bf16x8 bf10 = *(const bf16x8*)&sB[cb][(4 * 64 + l) * 8];
        bf16x8 bf11 = *(const bf16x8*)&sB[cb][(5 * 64 + l) * 8];
        bf16x8 bf12 = *(const bf16x8*)&sB[cb][(6 * 64 + l) * 8];
        bf16x8 bf13 = *(const bf16x8*)&sB[cb][(7 * 64 + l) * 8];

        // write staged regs (chunk c+1) into other buffer
        if (c < 15) {
            *(u16x8*)&sB[cb ^ 1][tid * 8]         = stg0;
            *(u16x8*)&sB[cb ^ 1][(256 + tid) * 8] = stg1;
        }
        // prefetch chunk c+2 (global, overlaps MFMA)
        if (c < 14) {
            stg0 = Bsrc[(c + 2) * 512 + tid];
            stg1 = Bsrc[(c + 2) * 512 + 256 + tid];
        }
        bf16x8 ca0 = a0, ca1 = a1;
        if (c < 15) {
            a0 = Asrc[(2 * (c + 1)) * 256];
            a1 = Asrc[(2 * (c + 1) + 1) * 256];
        }

        acc[0] = __builtin_amdgcn_mfma_f32_16x16x32_bf16(ca0, bf00, acc[0], 0, 0, 0);
        acc[1] = __builtin_amdgcn_mfma_f32_16x16x32_bf16(ca0, bf01, acc[1], 0, 0, 0);
        acc[2] = __builtin_amdgcn_mfma_f32_16x16x32_bf16(ca0, bf02, acc[2], 0, 0, 0);
        acc[3] = __builtin_amdgcn_mfma_f32_16x16x32_bf16(ca0, bf03, acc[3], 0, 0, 0);
        acc[0] = __builtin_amdgcn_mfma_f32_16x16x32_bf16(ca1, bf10, acc[0], 0, 0, 0);
        acc[1] = __builtin_amdgcn_mfma_f32_16x16x32_bf16(ca1, bf11, acc[1], 0, 0, 0);
        acc[2] = __builtin_amdgcn_mfma_f32_16x16x32_bf16(ca1, bf12, acc[2], 0, 0, 0);
        acc[3] = __builtin_amdgcn_mfma_f32_16x16x32_bf16(ca1, bf13, acc[3], 0, 0, 0);

        __syncthreads();
    }

    // ---- lane-local cell update (all 4 gates in-lane) ----
    {
        const int jj   = l & 15;
        const int hid  = nb * 16 + jj;
        const int rowb = mb * 64 + wv * 16 + (l >> 4) * 4;
        const int kc   = nb >> 1;
        const int hgrp = ((nb & 1) << 1) | (jj >> 3);
        const int ii   = jj & 7;
        #pragma unroll
        for (int r = 0; r < 4; ++r) {
            int row = rowb + r;
            float gi = acc[0][r], gf = acc[1][r], gg = acc[2][r], go = acc[3][r];
            size_t off = (size_t)row * H + hid;
            float cv = sigf(gf) * cbuf[off] + sigf(gi) * tanh_fast(gg);
            cbuf[off] = cv;
            float hv = sigf(go) * tanh_fast(cv);
            unsigned short hb = f2bf(hv);
            hs_t[off] = hb;
            size_t poff = (size_t)mb * 65536 + kc * 2048 + wv * 512
                        + (hgrp * 16 + (row & 15)) * 8 + ii;
            Anext[poff] = hb;
        }
    }
}

// =====================================================================
// out_proj: out[b][t][o] = hs[t][b][:] @ Wo[:,o] + bo[o]   (hs bf16)
// =====================================================================
__global__ __launch_bounds__(256) void out_proj(
    const unsigned short* __restrict__ hs,  // [64][256][1024] bf16
    const float* __restrict__ Wo,           // [1024][16]
    const float* __restrict__ bo,
    float* __restrict__ out)                // [256][64][16]
{
    __shared__ float sWo[H * NOUT];
    const int tid = threadIdx.x;
    for (int idx = tid; idx < H * NOUT; idx += 256) sWo[idx] = Wo[idx];
    __syncthreads();

    const int o    = tid & 15;
    const int pl   = tid >> 4;
    const int pair = blockIdx.x * 16 + pl;   // b*64 + t
    const int b    = pair >> 6;
    const int t    = pair & 63;
    const unsigned short* hrow = hs + ((size_t)t * BS + b) * H;

    float acc = bo[o];
    for (int k = 0; k < H; k += 8) {
        u16x8 u = *(const u16x8*)&hrow[k];
        #pragma unroll
        for (int j = 0; j < 8; ++j)
            acc = fmaf(bf2f(u[j]), sWo[(k + j) * 16 + o], acc);
    }
    out[(size_t)pair * 16 + o] = acc;
}

// =====================================================================
extern "C" void kernel_launch(void* const* d_in, const int* in_sizes, int n_in,
                              void* d_out, int out_size, void* d_ws, size_t ws_size,
                              hipStream_t stream)
{
    const float* hist = (const float*)d_in[0];
    const float* act  = (const float*)d_in[1];
    const float* Wc   = (const float*)d_in[2];
    const float* bc   = (const float*)d_in[3];
    const float* Wh   = (const float*)d_in[4];
    const float* bh   = (const float*)d_in[5];
    const float* Wi   = (const float*)d_in[6];
    const float* Wr   = (const float*)d_in[7];
    const float* bg   = (const float*)d_in[8];
    const float* Wo   = (const float*)d_in[9];
    const float* bo   = (const float*)d_in[10];
    float* out = (float*)d_out;

    char* W = (char*)d_ws;
    float*          cbuf = (float*)W;
    unsigned short* Wrp  = (unsigned short*)(W + OFF_WRP);
    unsigned short* Wip  = (unsigned short*)(W + OFF_WIP);
    float*          bgp  = (float*)(W + OFF_BGP);
    unsigned short* hpA  = (unsigned short*)(W + OFF_HPA);
    unsigned short* hpB  = (unsigned short*)(W + OFF_HPB);
    unsigned short* hs   = (unsigned short*)(W + OFF_HS);
    float*          part = (float*)(W + OFF_PART);   // overlays hs t>=48 (consumed first)

    pack_wr<<<dim3(2048), dim3(256), 0, stream>>>(Wr, Wrp);
    pack_wi<<<dim3(64),   dim3(256), 0, stream>>>(Wi, Wip);
    pack_bg<<<dim3(16),   dim3(256), 0, stream>>>(bg, bgp);

    init_gemm_sk<<<dim3(1024), dim3(256), 0, stream>>>(hist, Wc, Wh, part);
    reduce_pack<<<dim3(2048), dim3(256), 0, stream>>>(part, bc, bh, cbuf, hpA);

    for (int t = 0; t < T_STEPS; ++t) {
        const unsigned short* Ap = (t & 1) ? hpB : hpA;
        unsigned short*       An = (t & 1) ? hpA : hpB;
        lstm_step<<<dim3(256), dim3(256), 0, stream>>>(
            act, Wip, Wrp, bgp, Ap, An, cbuf, hs + (size_t)t * BS * H, t);
    }

    out_proj<<<dim3(1024), dim3(256), 0, stream>>>(hs, Wo, bo, out);
}

// Round 6
// 729.522 us; speedup vs baseline: 5.9589x; 1.1175x over previous
//
#include <hip/hip_runtime.h>
#include <math.h>

// Problem dims (fixed by reference)
#define BS      256
#define FLAT    8192
#define H       1024
#define G4      4096
#define T_STEPS 64
#define AD      16
#define NOUT    16

typedef __attribute__((ext_vector_type(8))) short    bf16x8;   // MFMA A/B frag
typedef __attribute__((ext_vector_type(4))) float    f32x4;    // MFMA C/D frag
typedef __attribute__((ext_vector_type(8))) unsigned short u16x8;
typedef __attribute__((ext_vector_type(4))) unsigned short u16x4;

__device__ __forceinline__ float sigf(float x) { return 1.0f / (1.0f + __expf(-x)); }
__device__ __forceinline__ float tanh_fast(float x) {
    float a = fabsf(x);
    float e = __expf(-2.0f * a);
    float r = (1.0f - e) / (1.0f + e);
    return copysignf(r, x);
}
__device__ __forceinline__ unsigned short f2bf(float x) {   // RNE
    unsigned int u = __float_as_uint(x);
    unsigned int r = (u + 0x7FFFu + ((u >> 16) & 1u)) >> 16;
    return (unsigned short)r;
}
__device__ __forceinline__ float bf2f(unsigned short u) {
    return __uint_as_float(((unsigned int)u) << 16);
}

// ws layout (bytes), total ~55.3 MB (ws >= 66 MB proven in round 2)
#define OFF_WRP  (1u<<20)                        // Wr packed bf16, 8 MB
#define OFF_WIP  (OFF_WRP + (8u<<20))            // Wi packed bf16, 256 KB
#define OFF_BGP  (OFF_WIP + (256u<<10))          // bg packed f32, 16 KB
#define OFF_HPA  (OFF_BGP + (16u<<10))           // h packed ping, 512 KB
#define OFF_HPB  (OFF_HPA + (512u<<10))          // h packed pong, 512 KB
#define OFF_HS   (OFF_HPB + (512u<<10))          // hs bf16 [64][256][1024], 32 MB
                                                 // (Bwp = packed Wc|Wh overlays OFF_HS:
                                                 //  consumed by init GEMM before step 0)
#define OFF_AHP  (OFF_HS + (32u<<20))            // hist packed bf16, 4 MB
#define OFF_AXP  (OFF_AHP + (4u<<20))            // action packed bf16, 1 MB
#define OFF_PART (OFF_AXP + (1u<<20))            // init split-K partials f32, 8 MB

// =====================================================================
// Wr pack (verified r4): Wp[nb][kc][l][i] = Wr[kc*32+(l>>4)*8+i][gatecol]
// =====================================================================
__global__ __launch_bounds__(256) void pack_wr(const float* __restrict__ Wr,
                                               unsigned short* __restrict__ Wp)
{
    int g  = blockIdx.x * 256 + threadIdx.x;     // 0..524287
    int l  = g & 63;
    int nt = (g >> 6) & 3;
    int kc = (g >> 8) & 31;
    int nb = g >> 13;
    int col   = nt * 1024 + nb * 16 + (l & 15);
    int kbase = kc * 32 + (l >> 4) * 8;
    u16x8 o;
    #pragma unroll
    for (int i = 0; i < 8; ++i)
        o[i] = f2bf(Wr[(size_t)(kbase + i) * G4 + col]);
    *(u16x8*)&Wp[(size_t)g * 8] = o;
}

// Wi pack (K zero-padded 16->32), verified r4.
__global__ __launch_bounds__(256) void pack_wi(const float* __restrict__ Wi,
                                               unsigned short* __restrict__ Wp)
{
    int g  = blockIdx.x * 256 + threadIdx.x;     // 0..16383
    int l  = g & 63;
    int nt = (g >> 6) & 3;
    int nb = g >> 8;
    int col   = nt * 1024 + nb * 16 + (l & 15);
    int kbase = (l >> 4) * 8;
    u16x8 o;
    #pragma unroll
    for (int i = 0; i < 8; ++i)
        o[i] = (kbase + i < AD) ? f2bf(Wi[(size_t)(kbase + i) * G4 + col]) : (unsigned short)0;
    *(u16x8*)&Wp[(size_t)g * 8] = o;
}

// bg pack, verified r4.
__global__ __launch_bounds__(256) void pack_bg(const float* __restrict__ bg,
                                               float* __restrict__ bgp)
{
    int t = blockIdx.x * 256 + threadIdx.x;      // 0..4095
    int jj = t & 15, nt = (t >> 4) & 3, nb = t >> 6;
    bgp[t] = bg[nt * 1024 + nb * 16 + jj];
}

// =====================================================================
// hist -> A-frag-linear bf16: Ap[mb16][kc256][l][i] = hist[mb*16+(l&15)][kc*32+(l>>4)*8+i]
// =====================================================================
__global__ __launch_bounds__(256) void pack_hist(const float* __restrict__ hist,
                                                 unsigned short* __restrict__ Ap)
{
    int g  = blockIdx.x * 256 + threadIdx.x;     // 0..262143 (grid 1024)
    int l  = g & 63;
    int kc = (g >> 6) & 255;
    int mb = g >> 14;
    const float* src = hist + (size_t)(mb * 16 + (l & 15)) * FLAT + kc * 32 + (l >> 4) * 8;
    float4 v0 = *(const float4*)src;
    float4 v1 = *(const float4*)(src + 4);
    u16x8 o;
    o[0]=f2bf(v0.x); o[1]=f2bf(v0.y); o[2]=f2bf(v0.z); o[3]=f2bf(v0.w);
    o[4]=f2bf(v1.x); o[5]=f2bf(v1.y); o[6]=f2bf(v1.z); o[7]=f2bf(v1.w);
    *(u16x8*)&Ap[(size_t)g * 8] = o;
}

// =====================================================================
// Wc|Wh -> B-frag-linear bf16: Bp[nb128][kc256][l][i] = W[kc*32+(l>>4)*8+i][(nb&63)*16+(l&15)]
// nb<64 -> Wc, nb>=64 -> Wh.
// =====================================================================
__global__ __launch_bounds__(256) void pack_wb(const float* __restrict__ Wc,
                                               const float* __restrict__ Wh,
                                               unsigned short* __restrict__ Bp)
{
    int g  = blockIdx.x * 256 + threadIdx.x;     // 0..2097151 (grid 8192)
    int l  = g & 63;
    int kc = (g >> 6) & 255;
    int nb = g >> 14;
    const float* src = (nb & 64) ? Wh : Wc;
    int n = (nb & 63) * 16 + (l & 15);
    int k = kc * 32 + (l >> 4) * 8;
    u16x8 o;
    #pragma unroll
    for (int i = 0; i < 8; ++i)
        o[i] = f2bf(src[(size_t)(k + i) * H + n]);
    *(u16x8*)&Bp[(size_t)g * 8] = o;
}

// =====================================================================
// action -> A-frag-linear bf16, K zero-padded 16->32:
// Axp[t][q16][l][i] = act[q*16+(l&15)][t][(l>>4)*8+i]  (q = mb*4+wv)
// =====================================================================
__global__ __launch_bounds__(256) void pack_act(const float* __restrict__ act,
                                                unsigned short* __restrict__ Axp)
{
    int g = blockIdx.x * 256 + threadIdx.x;      // 0..65535 (grid 256)
    int l = g & 63;
    int q = (g >> 6) & 15;
    int t = g >> 10;
    int row = q * 16 + (l & 15);
    int kb  = (l >> 4) * 8;
    u16x8 o;
    if (kb < AD) {
        const float* src = act + ((size_t)row * T_STEPS + t) * AD + kb;
        float4 v0 = *(const float4*)src;
        float4 v1 = *(const float4*)(src + 4);
        o[0]=f2bf(v0.x); o[1]=f2bf(v0.y); o[2]=f2bf(v0.z); o[3]=f2bf(v0.w);
        o[4]=f2bf(v1.x); o[5]=f2bf(v1.y); o[6]=f2bf(v1.z); o[7]=f2bf(v1.w);
    } else {
        o = (u16x8){0,0,0,0,0,0,0,0};
    }
    *(u16x8*)&Axp[(size_t)g * 8] = o;
}

// =====================================================================
// init GEMM, MFMA bf16, LDS-free, split-K x4.
// grid 256 = mb(4: 64 rows) x nbl(16: 128 cols of 2048) x ks(4: K 2048).
// block 256 = 4 waves (wm2 x wn2), wave tile M32 x N64 (2 m-frags x 4 n-frags).
// Writes partials f32 [ks][256][2048] (no bias yet).
// =====================================================================
__global__ __launch_bounds__(256) void init_gemm_mfma(
    const unsigned short* __restrict__ Ap,    // packed hist
    const unsigned short* __restrict__ Bp,    // packed Wc|Wh
    float* __restrict__ part)                 // [4][256][2048]
{
    const int wg  = blockIdx.x;
    const int mb  = wg & 3;
    const int nbl = (wg >> 2) & 15;
    const int ks  = wg >> 6;
    const int tid = threadIdx.x;
    const int wv  = tid >> 6;
    const int l   = tid & 63;
    const int wm  = wv & 1;
    const int wn  = wv >> 1;

    const bf16x8* AV = (const bf16x8*)Ap;
    const bf16x8* BV = (const bf16x8*)Bp;
    const int am0 = mb * 4 + wm * 2;            // 16-row blocks
    const int bn0 = nbl * 8 + wn * 4;           // 16-col blocks
    const bf16x8* A0 = AV + (size_t)am0 * 16384 + l;
    const bf16x8* A1 = A0 + 16384;
    const bf16x8* B0 = BV + (size_t)bn0 * 16384 + l;
    const bf16x8* B1 = B0 + 16384;
    const bf16x8* B2 = B1 + 16384;
    const bf16x8* B3 = B2 + 16384;

    const int k0 = ks * 64;                     // 64 K-chunks of 32
    f32x4 acc[2][4];
    #pragma unroll
    for (int m = 0; m < 2; ++m)
        #pragma unroll
        for (int n = 0; n < 4; ++n)
            acc[m][n] = (f32x4){0.f, 0.f, 0.f, 0.f};

    bf16x8 a0 = A0[(size_t)k0 * 64], a1 = A1[(size_t)k0 * 64];
    bf16x8 b0 = B0[(size_t)k0 * 64], b1 = B1[(size_t)k0 * 64];
    bf16x8 b2 = B2[(size_t)k0 * 64], b3 = B3[(size_t)k0 * 64];

    for (int kc = k0; kc < k0 + 64; ++kc) {
        bf16x8 na0, na1, nb0, nb1, nb2, nb3;
        const bool more = (kc + 1) < k0 + 64;
        if (more) {
            size_t off = (size_t)(kc + 1) * 64;
            na0 = A0[off]; na1 = A1[off];
            nb0 = B0[off]; nb1 = B1[off]; nb2 = B2[off]; nb3 = B3[off];
        }
        acc[0][0] = __builtin_amdgcn_mfma_f32_16x16x32_bf16(a0, b0, acc[0][0], 0, 0, 0);
        acc[0][1] = __builtin_amdgcn_mfma_f32_16x16x32_bf16(a0, b1, acc[0][1], 0, 0, 0);
        acc[0][2] = __builtin_amdgcn_mfma_f32_16x16x32_bf16(a0, b2, acc[0][2], 0, 0, 0);
        acc[0][3] = __builtin_amdgcn_mfma_f32_16x16x32_bf16(a0, b3, acc[0][3], 0, 0, 0);
        acc[1][0] = __builtin_amdgcn_mfma_f32_16x16x32_bf16(a1, b0, acc[1][0], 0, 0, 0);
        acc[1][1] = __builtin_amdgcn_mfma_f32_16x16x32_bf16(a1, b1, acc[1][1], 0, 0, 0);
        acc[1][2] = __builtin_amdgcn_mfma_f32_16x16x32_bf16(a1, b2, acc[1][2], 0, 0, 0);
        acc[1][3] = __builtin_amdgcn_mfma_f32_16x16x32_bf16(a1, b3, acc[1][3], 0, 0, 0);
        if (more) { a0 = na0; a1 = na1; b0 = nb0; b1 = nb1; b2 = nb2; b3 = nb3; }
    }

    // epilogue: C layout col=l&15, row=(l>>4)*4+r (verified r4)
    const int rbase = mb * 64 + wm * 32 + (l >> 4) * 4;
    const int cbase = nbl * 128 + wn * 64 + (l & 15);
    float* pdst = part + (size_t)ks * (BS * 2048);
    #pragma unroll
    for (int m = 0; m < 2; ++m)
        #pragma unroll
        for (int n = 0; n < 4; ++n)
            #pragma unroll
            for (int r = 0; r < 4; ++r)
                pdst[(size_t)(rbase + m * 16 + r) * 2048 + cbase + n * 16] = acc[m][n][r];
}

// reduce partials + bias + relu; cols<1024 -> cbuf f32; cols>=1024 -> hpA packed bf16
__global__ __launch_bounds__(256) void init_reduce(
    const float* __restrict__ part,
    const float* __restrict__ bc, const float* __restrict__ bh,
    float* __restrict__ cbuf, unsigned short* __restrict__ hp0)
{
    int e = blockIdx.x * 256 + threadIdx.x;      // 0..524287 (grid 2048)
    int row = e >> 11, col = e & 2047;
    float s = (col < 1024) ? bc[col] : bh[col - 1024];
    #pragma unroll
    for (int ks = 0; ks < 4; ++ks)
        s += part[(size_t)ks * (BS * 2048) + e];
    s = fmaxf(s, 0.f);
    if (col < 1024) {
        cbuf[(size_t)row * H + col] = s;
    } else {
        int hid = col - 1024;
        int off = (row >> 6) * 65536 + (hid >> 5) * 2048 + ((row >> 4) & 3) * 512
                + ((((hid >> 3) & 3) << 4) + (row & 15)) * 8 + (hid & 7);
        hp0[off] = f2bf(s);
    }
}

// =====================================================================
// LSTM step, MFMA bf16 (structure verified r4; changes: Axp direct A-frag
// for the Wi term, A prefetch depth 2 with statically-named reg sets).
// grid 256 = mb(4) x nb(64); block 256 = 4 waves, wave = 16 rows x 64 gate-cols.
// =====================================================================
__global__ __launch_bounds__(256) void lstm_step(
    const unsigned short* __restrict__ Axp,   // action packed
    const unsigned short* __restrict__ Wip,   // packed
    const unsigned short* __restrict__ Wrp,   // packed
    const float* __restrict__ bgp,            // packed
    const unsigned short* __restrict__ Aprev, // h_{t-1} packed bf16
    unsigned short* __restrict__ Anext,       // h_t packed bf16
    float* __restrict__ cbuf,                 // [256][1024] f32 RMW
    unsigned short* __restrict__ hs_t,        // hs + t*BS*H (bf16)
    int t)
{
    __shared__ __align__(16) unsigned short sB[2][4096];   // 2 x 8KB

    const int tid = threadIdx.x;
    const int wg  = blockIdx.x;
    const int mb  = wg >> 6;
    const int nb  = wg & 63;
    const int wv  = tid >> 6;
    const int l   = tid & 63;

    // ---- B staging: chunk 0 -> LDS buf0; chunk 1 -> regs ----
    const u16x8* Bsrc = (const u16x8*)(Wrp + (size_t)nb * 65536);
    {
        u16x8 s0 = Bsrc[tid], s1 = Bsrc[256 + tid];
        *(u16x8*)&sB[0][tid * 8]         = s0;
        *(u16x8*)&sB[0][(256 + tid) * 8] = s1;
    }
    u16x8 stg0 = Bsrc[512 + tid];
    u16x8 stg1 = Bsrc[768 + tid];

    // ---- A frags: preload chunks 0 (E) and 1 (O) ----
    const bf16x8* Asrc = ((const bf16x8*)Aprev) + mb * 8192 + wv * 64 + l;
    bf16x8 aE0 = Asrc[0],   aE1 = Asrc[256];
    bf16x8 aO0 = Asrc[512], aO1 = Asrc[768];

    // ---- bias init + Wi MFMA (A-frag straight from Axp, no LDS) ----
    f32x4 acc[4];
    {
        const bf16x8* WiB = ((const bf16x8*)Wip) + nb * 256;
        bf16x8 wb0 = WiB[0 * 64 + l], wb1 = WiB[1 * 64 + l],
               wb2 = WiB[2 * 64 + l], wb3 = WiB[3 * 64 + l];
        float g0 = bgp[nb * 64 +  0 + (l & 15)];
        float g1 = bgp[nb * 64 + 16 + (l & 15)];
        float g2 = bgp[nb * 64 + 32 + (l & 15)];
        float g3 = bgp[nb * 64 + 48 + (l & 15)];
        acc[0] = (f32x4){ g0, g0, g0, g0 };
        acc[1] = (f32x4){ g1, g1, g1, g1 };
        acc[2] = (f32x4){ g2, g2, g2, g2 };
        acc[3] = (f32x4){ g3, g3, g3, g3 };

        bf16x8 aa = *(((const bf16x8*)Axp) + ((size_t)t * 16 + mb * 4 + wv) * 64 + l);
        acc[0] = __builtin_amdgcn_mfma_f32_16x16x32_bf16(aa, wb0, acc[0], 0, 0, 0);
        acc[1] = __builtin_amdgcn_mfma_f32_16x16x32_bf16(aa, wb1, acc[1], 0, 0, 0);
        acc[2] = __builtin_amdgcn_mfma_f32_16x16x32_bf16(aa, wb2, acc[2], 0, 0, 0);
        acc[3] = __builtin_amdgcn_mfma_f32_16x16x32_bf16(aa, wb3, acc[3], 0, 0, 0);
    }
    __syncthreads();   // sB[0] visible

    // ---- main K loop: 16 chunks of BK=64, unroll 2 (even/odd named sets) ----
    #define CHUNK_BODY(C, CB, AX0, AX1)                                             \
    {                                                                               \
        bf16x8 n0, n1;                                                              \
        if ((C) < 14) { n0 = Asrc[(2*(C)+4) * 256]; n1 = Asrc[(2*(C)+5) * 256]; }   \
        bf16x8 bf00 = *(const bf16x8*)&sB[CB][(0 * 64 + l) * 8];                    \
        bf16x8 bf01 = *(const bf16x8*)&sB[CB][(1 * 64 + l) * 8];                    \
        bf16x8 bf02 = *(const bf16x8*)&sB[CB][(2 * 64 + l) * 8];                    \
        bf16x8 bf03 = *(const bf16x8*)&sB[CB][(3 * 64 + l) * 8];                    \
        bf16x8 bf10 = *(const bf16x8*)&sB[CB][(4 * 64 + l) * 8];                    \
        bf16x8 bf11 = *(const bf16x8*)&sB[CB][(5 * 64 + l) * 8];                    \
        bf16x8 bf12 = *(const bf16x8*)&sB[CB][(6 * 64 + l) * 8];                    \
        bf16x8 bf13 = *(const bf16x8*)&sB[CB][(7 * 64 + l) * 8];                    \
        if ((C) < 15) {                                                             \
            *(u16x8*)&sB[(CB) ^ 1][tid * 8]         = stg0;                         \
            *(u16x8*)&sB[(CB) ^ 1][(256 + tid) * 8] = stg1;                         \
        }                                                                           \
        if ((C) < 14) {                                                             \
            stg0 = Bsrc[((C) + 2) * 512 + tid];                                     \
            stg1 = Bsrc[((C) + 2) * 512 + 256 + tid];                               \
        }                                                                           \
        acc[0] = __builtin_amdgcn_mfma_f32_16x16x32_bf16(AX0, bf00, acc[0], 0,0,0); \
        acc[1] = __builtin_amdgcn_mfma_f32_16x16x32_bf16(AX0, bf01, acc[1], 0,0,0); \
        acc[2] = __builtin_amdgcn_mfma_f32_16x16x32_bf16(AX0, bf02, acc[2], 0,0,0); \
        acc[3] = __builtin_amdgcn_mfma_f32_16x16x32_bf16(AX0, bf03, acc[3], 0,0,0); \
        acc[0] = __builtin_amdgcn_mfma_f32_16x16x32_bf16(AX1, bf10, acc[0], 0,0,0); \
        acc[1] = __builtin_amdgcn_mfma_f32_16x16x32_bf16(AX1, bf11, acc[1], 0,0,0); \
        acc[2] = __builtin_amdgcn_mfma_f32_16x16x32_bf16(AX1, bf12, acc[2], 0,0,0); \
        acc[3] = __builtin_amdgcn_mfma_f32_16x16x32_bf16(AX1, bf13, acc[3], 0,0,0); \
        if ((C) < 14) { AX0 = n0; AX1 = n1; }                                       \
        __syncthreads();                                                            \
    }

    for (int it = 0; it < 8; ++it) {
        const int c0 = 2 * it;
        CHUNK_BODY(c0,     0, aE0, aE1)
        CHUNK_BODY(c0 + 1, 1, aO0, aO1)
    }
    #undef CHUNK_BODY

    // ---- lane-local cell update (all 4 gates in-lane), verified r4 ----
    {
        const int jj   = l & 15;
        const int hid  = nb * 16 + jj;
        const int rowb = mb * 64 + wv * 16 + (l >> 4) * 4;
        const int kc   = nb >> 1;
        const int hgrp = ((nb & 1) << 1) | (jj >> 3);
        const int ii   = jj & 7;
        #pragma unroll
        for (int r = 0; r < 4; ++r) {
            int row = rowb + r;
            float gi = acc[0][r], gf = acc[1][r], gg = acc[2][r], go = acc[3][r];
            size_t off = (size_t)row * H + hid;
            float cv = sigf(gf) * cbuf[off] + sigf(gi) * tanh_fast(gg);
            cbuf[off] = cv;
            float hv = sigf(go) * tanh_fast(cv);
            unsigned short hb = f2bf(hv);
            hs_t[off] = hb;
            size_t poff = (size_t)mb * 65536 + kc * 2048 + wv * 512
                        + (hgrp * 16 + (row & 15)) * 8 + ii;
            Anext[poff] = hb;
        }
    }
}

// =====================================================================
// out_proj: 256 WGs x 64 pairs (cuts Wo staging traffic 4x vs r4)
// =====================================================================
__global__ __launch_bounds__(256) void out_proj(
    const unsigned short* __restrict__ hs,  // [64][256][1024] bf16
    const float* __restrict__ Wo,           // [1024][16]
    const float* __restrict__ bo,
    float* __restrict__ out)                // [256][64][16]
{
    __shared__ float sWo[H * NOUT];
    const int tid = threadIdx.x;
    for (int idx = tid; idx < H * NOUT; idx += 256) sWo[idx] = Wo[idx];
    __syncthreads();

    const int o  = tid & 15;
    const int pl = tid >> 4;
    const float bias = bo[o];
    #pragma unroll
    for (int pass = 0; pass < 4; ++pass) {
        const int pair = blockIdx.x * 64 + pass * 16 + pl;   // b*64 + t
        const int b = pair >> 6;
        const int t = pair & 63;
        const unsigned short* hrow = hs + ((size_t)t * BS + b) * H;
        float acc = bias;
        for (int k = 0; k < H; k += 8) {
            u16x8 u = *(const u16x8*)&hrow[k];
            #pragma unroll
            for (int j = 0; j < 8; ++j)
                acc = fmaf(bf2f(u[j]), sWo[(k + j) * 16 + o], acc);
        }
        out[(size_t)pair * 16 + o] = acc;
    }
}

// =====================================================================
extern "C" void kernel_launch(void* const* d_in, const int* in_sizes, int n_in,
                              void* d_out, int out_size, void* d_ws, size_t ws_size,
                              hipStream_t stream)
{
    const float* hist = (const float*)d_in[0];
    const float* act  = (const float*)d_in[1];
    const float* Wc   = (const float*)d_in[2];
    const float* bc   = (const float*)d_in[3];
    const float* Wh   = (const float*)d_in[4];
    const float* bh   = (const float*)d_in[5];
    const float* Wi   = (const float*)d_in[6];
    const float* Wr   = (const float*)d_in[7];
    const float* bg   = (const float*)d_in[8];
    const float* Wo   = (const float*)d_in[9];
    const float* bo   = (const float*)d_in[10];
    float* out = (float*)d_out;

    char* W = (char*)d_ws;
    float*          cbuf = (float*)W;
    unsigned short* Wrp  = (unsigned short*)(W + OFF_WRP);
    unsigned short* Wip  = (unsigned short*)(W + OFF_WIP);
    float*          bgp  = (float*)(W + OFF_BGP);
    unsigned short* hpA  = (unsigned short*)(W + OFF_HPA);
    unsigned short* hpB  = (unsigned short*)(W + OFF_HPB);
    unsigned short* hs   = (unsigned short*)(W + OFF_HS);
    unsigned short* Bwp  = (unsigned short*)(W + OFF_HS);   // overlay: consumed pre-scan
    unsigned short* Ahp  = (unsigned short*)(W + OFF_AHP);
    unsigned short* Axp  = (unsigned short*)(W + OFF_AXP);
    float*          part = (float*)(W + OFF_PART);

    pack_wr  <<<dim3(2048), dim3(256), 0, stream>>>(Wr, Wrp);
    pack_wi  <<<dim3(64),   dim3(256), 0, stream>>>(Wi, Wip);
    pack_bg  <<<dim3(16),   dim3(256), 0, stream>>>(bg, bgp);
    pack_hist<<<dim3(1024), dim3(256), 0, stream>>>(hist, Ahp);
    pack_wb  <<<dim3(8192), dim3(256), 0, stream>>>(Wc, Wh, Bwp);
    pack_act <<<dim3(256),  dim3(256), 0, stream>>>(act, Axp);

    init_gemm_mfma<<<dim3(256), dim3(256), 0, stream>>>(Ahp, Bwp, part);
    init_reduce  <<<dim3(2048), dim3(256), 0, stream>>>(part, bc, bh, cbuf, hpA);

    for (int t = 0; t < T_STEPS; ++t) {
        const unsigned short* Ap = (t & 1) ? hpB : hpA;
        unsigned short*       An = (t & 1) ? hpA : hpB;
        lstm_step<<<dim3(256), dim3(256), 0, stream>>>(
            Axp, Wip, Wrp, bgp, Ap, An, cbuf, hs + (size_t)t * BS * H, t);
    }

    out_proj<<<dim3(256), dim3(256), 0, stream>>>(hs, Wo, bo, out);
}